// Round 6
// baseline (78.333 us; speedup 1.0000x reference)
//
#include <hip/hip_runtime.h>
#include <hip/hip_bf16.h>

#define NSPK 1024
#define MU 32
#define DIM 512
#define DIMP (DIM + 8)
#define NROW (NSPK * MU)   // 32768
#define EPS 1e-6f

typedef __attribute__((ext_vector_type(4))) float f32x4;
typedef __attribute__((ext_vector_type(8))) short bf16x8;

#define GLOAD_LDS16(g, l)                                          \
  __builtin_amdgcn_global_load_lds(                                \
      (const __attribute__((address_space(1))) void*)(g),          \
      (__attribute__((address_space(3))) void*)(l), 16, 0, 0)

__device__ inline ushort f2bf(float x) {
  __hip_bfloat16 h = __float2bfloat16(x);
  return *reinterpret_cast<ushort*>(&h);
}

// ---------------------------------------------------------------------------
// Kernel 1: per-speaker prep. LOO cosines (fp32 exact) + normalized bf16
// A and B written in MFMA-FRAGMENT-MAJOR layout:
//   frag(rb,kf) [A] / frag(nb,kf) [B] = 512 ushorts; lane l holds
//   row/col = base16 + (l&15), k = kf*32 + (l>>4)*8 .. +8   (16 B chunk)
// grid = NSPK, block = 256
// ---------------------------------------------------------------------------
__global__ __launch_bounds__(256) void k_prep(
    const float* __restrict__ dvecs,
    ushort* __restrict__ Af,    // [2048 rb][16 kf][64 lane][8]
    ushort* __restrict__ Bf,    // [64 nb][16 kf][64 lane][8]
    float* __restrict__ loo)    // [NROW]
{
  const int j = blockIdx.x, t = threadIdx.x;
  __shared__ float sD[MU * DIMP];   // padded raw speaker rows (66.5 KiB)
  __shared__ float sS[DIM];
  __shared__ float sred[4];
  __shared__ float sS2v;
  __shared__ float sInv[MU];

  const float* base = dvecs + (size_t)j * (MU * DIM);

  // single global read: stage rows + column sums
  float s0 = 0.f, s1 = 0.f;
  for (int m = 0; m < MU; ++m) {
    float a = base[m * DIM + t];
    float b = base[m * DIM + t + 256];
    sD[m * DIMP + t] = a;
    sD[m * DIMP + t + 256] = b;
    s0 += a; s1 += b;
  }
  sS[t] = s0; sS[t + 256] = s1;
  __syncthreads();

  // |S|^2
  float p = s0 * s0 + s1 * s1;
  for (int off = 32; off; off >>= 1) p += __shfl_down(p, off);
  if ((t & 63) == 0) sred[t >> 6] = p;
  __syncthreads();
  if (t == 0) sS2v = sred[0] + sred[1] + sred[2] + sred[3];
  __syncthreads();
  const float S2 = sS2v;

  // per-utterance dot(e,S), |e|^2 from LDS (8 lanes per row)
  const int g = t >> 3, l = t & 7;
  float dotS = 0.f, e2 = 0.f;
  for (int i = 0; i < DIM / 8; ++i) {
    int d = i * 8 + l;
    float ev = sD[g * DIMP + d];
    dotS += ev * sS[d];
    e2 += ev * ev;
  }
  for (int off = 4; off; off >>= 1) {
    dotS += __shfl_down(dotS, off);
    e2 += __shfl_down(e2, off);
  }
  if (l == 0) {
    float numer = dotS - e2;                          // e.(S-e)
    float d2 = fmaxf(S2 - 2.f * dotS + e2, 1e-30f);   // |S-e|^2
    loo[j * MU + g] = numer / (sqrtf(e2) * sqrtf(d2));
    sInv[g] = 1.f / sqrtf(e2);
  }
  __syncthreads();

  // A fragments: this speaker = rows j*32..+31 = rb j*2, j*2+1
  for (int i = 0; i < 8; ++i) {
    int idx = i * 256 + t;          // 0..2047 16B-chunks
    int fragL = idx >> 6;           // 0..31 (rbl*16 + kf)
    int lane2 = idx & 63;
    int rbl = fragL >> 4, kf = fragL & 15;
    int m = rbl * 16 + (lane2 & 15);
    int k0 = kf * 32 + (lane2 >> 4) * 8;
    float inv = sInv[m];
    ushort tmp[8];
#pragma unroll
    for (int z = 0; z < 8; ++z) tmp[z] = f2bf(sD[m * DIMP + k0 + z] * inv);
    *(bf16x8*)&Af[(((size_t)(j * 2 + rbl) * 16 + kf) << 9) + lane2 * 8] =
        *(bf16x8*)tmp;
  }

  // B fragment pieces for centroid j (col j -> lane&15 = j&15)
  if (t < 64) {
    int kf = t >> 2, q = t & 3;
    int lane2 = q * 16 + (j & 15);
    float invc = 1.f / sqrtf(S2);
    int k0 = kf * 32 + q * 8;
    ushort tmp[8];
#pragma unroll
    for (int z = 0; z < 8; ++z) tmp[z] = f2bf(sS[k0 + z] * invc);
    *(bf16x8*)&Bf[(((size_t)(j >> 4) * 16 + kf) << 9) + lane2 * 8] =
        *(bf16x8*)tmp;
  }
}

// ---------------------------------------------------------------------------
// Kernel 2: barrier-free fused cosine-GEMM.
// One block = 64 rows x ALL 1024 cols, 256 threads (4 waves); grid = 512 ->
// 2 blocks/CU (LDS 65 KiB) -> 2 waves/SIMD WITHOUT 512-thread blocks, which
// empirically pin VGPR_Count=128 and spill the accumulator (R4/R5: 69 MB
// scratch writes). 256-thread blocks got 220 VGPRs in R3 -> no spill.
// Each wave: one 256-col chunk, all 64 rows (4 mf), 2 sub-chunks of 8 nf
// (acc[4][8] = 128 VGPR). A panel LDS-resident (frag-linear, conflict-free);
// B fragments streamed global->registers (L2-resident, 1 MiB).
// grid = 512, block = 256
// ---------------------------------------------------------------------------
__global__ __launch_bounds__(256, 2) void k_gemm(
    const ushort* __restrict__ Af,
    const ushort* __restrict__ Bf,
    const float* __restrict__ wp,
    float* __restrict__ part,    // [NROW] sum of exp over all 1024 cols
    float* __restrict__ diag)    // [NROW] raw cos vs own full centroid
{
  __shared__ ushort ldsA[64 * DIM];    // 64 KiB, fragment-linear
  __shared__ float sPart[64][4];

  const int t = threadIdx.x;
  const int w = t >> 6, lane = t & 63;
  const int lr = lane & 15, lk = lane >> 4;
  const int rblk = blockIdx.x;         // 0..511
  const float W = *wp;

  // stage A panel once: 64 frags x 1 KiB, linear global_load_lds
  {
    const ushort* gsrc = Af + (size_t)rblk * (64 * DIM);
    const int off = t * 8;   // ushort units, lane-contiguous 16B
#pragma unroll
    for (int i = 0; i < 16; ++i)
      GLOAD_LDS16(gsrc + off + i * 2048, ((char*)ldsA) + (off + i * 2048) * 2);
  }
  __syncthreads();   // only barrier before epilogue

  float sum[4][4];
#pragma unroll
  for (int a = 0; a < 4; ++a)
#pragma unroll
    for (int b = 0; b < 4; ++b) sum[a][b] = 0.f;

#pragma unroll
  for (int sub = 0; sub < 2; ++sub) {
    f32x4 acc[4][8];
#pragma unroll
    for (int a = 0; a < 4; ++a)
#pragma unroll
      for (int b = 0; b < 8; ++b) acc[a][b] = (f32x4)0.f;

    // this sub-chunk's 8 B fragments; frag nb stride = 8192 ushorts (<<13)
    const ushort* bp0 = Bf + ((size_t)(w * 16 + sub * 8) << 13) + lane * 8;

#pragma unroll
    for (int kf = 0; kf < 16; ++kf) {
      bf16x8 bfr[8];
#pragma unroll
      for (int nf = 0; nf < 8; ++nf)
        bfr[nf] = *(const bf16x8*)(bp0 + (size_t)((nf * 16 + kf) << 9));
#pragma unroll
      for (int mf = 0; mf < 4; ++mf) {
        const bf16x8 afr =
            *(const bf16x8*)&ldsA[((mf * 16 + kf) << 9) + lane * 8];
#pragma unroll
        for (int nf = 0; nf < 8; ++nf)
          acc[mf][nf] = __builtin_amdgcn_mfma_f32_16x16x32_bf16(
              afr, bfr[nf], acc[mf][nf], 0, 0, 0);
      }
    }

    // fused epilogue: exp((fmax(cos,eps)-1)*W)  [shift w+b cancels in lse]
#pragma unroll
    for (int mf = 0; mf < 4; ++mf)
#pragma unroll
      for (int i = 0; i < 4; ++i) {
#pragma unroll
        for (int nf = 0; nf < 8; ++nf)
          sum[mf][i] += __expf((fmaxf(acc[mf][nf][i], EPS) - 1.f) * W);
      }

    // diag capture: block's 2 speakers c = rblk*2 + sp; col c lives in
    // wave w = c>>8, sub = (c>>7)&1, nf = (c>>4)&7, lanes lr == c&15;
    // its rows are mf = sp*2 + mh (mh=0,1).
#pragma unroll
    for (int sp = 0; sp < 2; ++sp) {
      const int c = rblk * 2 + sp;
      if (w == (c >> 8) && sub == ((c >> 7) & 1)) {
        const int nfo = (c >> 4) & 7;
#pragma unroll
        for (int mh = 0; mh < 2; ++mh) {
          f32x4 dsel = acc[sp * 2 + mh][0];
#pragma unroll
          for (int nf = 1; nf < 8; ++nf)
            if (nf == nfo) dsel = acc[sp * 2 + mh][nf];   // static idx only
          if (lr == (c & 15)) {
#pragma unroll
            for (int i = 0; i < 4; ++i)
              diag[rblk * 64 + (sp * 2 + mh) * 16 + lk * 4 + i] = dsel[i];
          }
        }
      }
    }
  }

  // reduce each row-sum across the 16 lr-lanes
#pragma unroll
  for (int mf = 0; mf < 4; ++mf)
#pragma unroll
    for (int i = 0; i < 4; ++i) {
      float v = sum[mf][i];
      v += __shfl_xor(v, 1);
      v += __shfl_xor(v, 2);
      v += __shfl_xor(v, 4);
      v += __shfl_xor(v, 8);
      sum[mf][i] = v;
    }
  if (lr == 0) {
#pragma unroll
    for (int mf = 0; mf < 4; ++mf)
#pragma unroll
      for (int i = 0; i < 4; ++i)
        sPart[mf * 16 + lk * 4 + i][w] = sum[mf][i];
  }
  __syncthreads();
  if (t < 64)
    part[rblk * 64 + t] =
        sPart[t][0] + sPart[t][1] + sPart[t][2] + sPart[t][3];
}

// ---------------------------------------------------------------------------
// Final: swap exp(diag)->exp(loo), close logsumexp, deterministic 2-stage sum
// L_row = log(part - exp(dt) + exp(lt)) - lt,  x_t = (fmax(x,eps)-1)*W
// ---------------------------------------------------------------------------
__global__ __launch_bounds__(256) void k_final1(
    const float* __restrict__ part, const float* __restrict__ loo,
    const float* __restrict__ diag, const float* __restrict__ wp,
    float* __restrict__ p2)
{
  const int t = threadIdx.x;
  const int r = blockIdx.x * 256 + t;
  const float W = *wp;
  const float lt = (fmaxf(loo[r], EPS) - 1.f) * W;
  const float dt = (fmaxf(diag[r], EPS) - 1.f) * W;
  const float s = part[r] + __expf(lt) - __expf(dt);
  float v = logf(s) - lt;
  __shared__ float red[4];
  for (int off = 32; off; off >>= 1) v += __shfl_down(v, off);
  if ((t & 63) == 0) red[t >> 6] = v;
  __syncthreads();
  if (t == 0) p2[blockIdx.x] = red[0] + red[1] + red[2] + red[3];
}

__global__ __launch_bounds__(128) void k_final2(
    const float* __restrict__ p2, float* __restrict__ out)
{
  const int t = threadIdx.x;
  float v = p2[t];
  for (int off = 32; off; off >>= 1) v += __shfl_down(v, off);
  __shared__ float red[2];
  if ((t & 63) == 0) red[t >> 6] = v;
  __syncthreads();
  if (t == 0) out[0] = red[0] + red[1];
}

extern "C" void kernel_launch(void* const* d_in, const int* in_sizes, int n_in,
                              void* d_out, int out_size, void* d_ws, size_t ws_size,
                              hipStream_t stream) {
  const float* dvecs = (const float*)d_in[0];
  const float* wptr  = (const float*)d_in[1];
  // b cancels algebraically (shift = w+b subtracted and re-added) -> unused
  float* out = (float*)d_out;

  char* ws = (char*)d_ws;
  ushort* Af = (ushort*)ws;  ws += (size_t)NROW * DIM * sizeof(ushort); // 32 MiB
  ushort* Bf = (ushort*)ws;  ws += (size_t)NSPK * DIM * sizeof(ushort); // 1 MiB
  float* loo  = (float*)ws;  ws += (size_t)NROW * sizeof(float);
  float* diag = (float*)ws;  ws += (size_t)NROW * sizeof(float);
  float* part = (float*)ws;  ws += (size_t)NROW * sizeof(float);
  float* p2   = (float*)ws;

  k_prep<<<NSPK, 256, 0, stream>>>(dvecs, Af, Bf, loo);
  k_gemm<<<512, 256, 0, stream>>>(Af, Bf, wptr, part, diag);
  k_final1<<<NROW / 256, 256, 0, stream>>>(part, loo, diag, wptr, p2);
  k_final2<<<1, 128, 0, stream>>>(p2, out);
}

// Round 7
// 75.565 us; speedup vs baseline: 1.0366x; 1.0366x over previous
//
#include <hip/hip_runtime.h>
#include <hip/hip_bf16.h>

#define NSPK 1024
#define MU 32
#define DIM 512
#define DIMP (DIM + 8)
#define NROW (NSPK * MU)   // 32768
#define EPS 1e-6f

typedef __attribute__((ext_vector_type(4))) float f32x4;
typedef __attribute__((ext_vector_type(8))) short bf16x8;

#define GLOAD_LDS16(g, l)                                          \
  __builtin_amdgcn_global_load_lds(                                \
      (const __attribute__((address_space(1))) void*)(g),          \
      (__attribute__((address_space(3))) void*)(l), 16, 0, 0)

__device__ inline ushort f2bf(float x) {
  __hip_bfloat16 h = __float2bfloat16(x);
  return *reinterpret_cast<ushort*>(&h);
}

// ---------------------------------------------------------------------------
// Kernel 1: per-speaker prep. LOO cosines (fp32 exact) + normalized bf16
// A and B written in MFMA-FRAGMENT-MAJOR layout:
//   frag(rb,kf) [A] / frag(nb,kf) [B] = 512 ushorts; lane l holds
//   row/col = base16 + (l&15), k = kf*32 + (l>>4)*8 .. +8   (16 B chunk)
// grid = NSPK, block = 256
// ---------------------------------------------------------------------------
__global__ __launch_bounds__(256) void k_prep(
    const float* __restrict__ dvecs,
    ushort* __restrict__ Af,    // [2048 rb][16 kf][64 lane][8]
    ushort* __restrict__ Bf,    // [64 nb][16 kf][64 lane][8]
    float* __restrict__ loo)    // [NROW]
{
  const int j = blockIdx.x, t = threadIdx.x;
  __shared__ float sD[MU * DIMP];   // padded raw speaker rows (66.5 KiB)
  __shared__ float sS[DIM];
  __shared__ float sred[4];
  __shared__ float sS2v;
  __shared__ float sInv[MU];

  const float* base = dvecs + (size_t)j * (MU * DIM);

  // single global read: stage rows + column sums
  float s0 = 0.f, s1 = 0.f;
  for (int m = 0; m < MU; ++m) {
    float a = base[m * DIM + t];
    float b = base[m * DIM + t + 256];
    sD[m * DIMP + t] = a;
    sD[m * DIMP + t + 256] = b;
    s0 += a; s1 += b;
  }
  sS[t] = s0; sS[t + 256] = s1;
  __syncthreads();

  // |S|^2
  float p = s0 * s0 + s1 * s1;
  for (int off = 32; off; off >>= 1) p += __shfl_down(p, off);
  if ((t & 63) == 0) sred[t >> 6] = p;
  __syncthreads();
  if (t == 0) sS2v = sred[0] + sred[1] + sred[2] + sred[3];
  __syncthreads();
  const float S2 = sS2v;

  // per-utterance dot(e,S), |e|^2 from LDS (8 lanes per row)
  const int g = t >> 3, l = t & 7;
  float dotS = 0.f, e2 = 0.f;
  for (int i = 0; i < DIM / 8; ++i) {
    int d = i * 8 + l;
    float ev = sD[g * DIMP + d];
    dotS += ev * sS[d];
    e2 += ev * ev;
  }
  for (int off = 4; off; off >>= 1) {
    dotS += __shfl_down(dotS, off);
    e2 += __shfl_down(e2, off);
  }
  if (l == 0) {
    float numer = dotS - e2;                          // e.(S-e)
    float d2 = fmaxf(S2 - 2.f * dotS + e2, 1e-30f);   // |S-e|^2
    loo[j * MU + g] = numer / (sqrtf(e2) * sqrtf(d2));
    sInv[g] = 1.f / sqrtf(e2);
  }
  __syncthreads();

  // A fragments: this speaker = rows j*32..+31 = rb j*2, j*2+1
  for (int i = 0; i < 8; ++i) {
    int idx = i * 256 + t;          // 0..2047 16B-chunks
    int fragL = idx >> 6;           // 0..31 (rbl*16 + kf)
    int lane2 = idx & 63;
    int rbl = fragL >> 4, kf = fragL & 15;
    int m = rbl * 16 + (lane2 & 15);
    int k0 = kf * 32 + (lane2 >> 4) * 8;
    float inv = sInv[m];
    ushort tmp[8];
#pragma unroll
    for (int z = 0; z < 8; ++z) tmp[z] = f2bf(sD[m * DIMP + k0 + z] * inv);
    *(bf16x8*)&Af[(((size_t)(j * 2 + rbl) * 16 + kf) << 9) + lane2 * 8] =
        *(bf16x8*)tmp;
  }

  // B fragment pieces for centroid j (col j -> lane&15 = j&15)
  if (t < 64) {
    int kf = t >> 2, q = t & 3;
    int lane2 = q * 16 + (j & 15);
    float invc = 1.f / sqrtf(S2);
    int k0 = kf * 32 + q * 8;
    ushort tmp[8];
#pragma unroll
    for (int z = 0; z < 8; ++z) tmp[z] = f2bf(sS[k0 + z] * invc);
    *(bf16x8*)&Bf[(((size_t)(j >> 4) * 16 + kf) << 9) + lane2 * 8] =
        *(bf16x8*)tmp;
  }
}

// ---------------------------------------------------------------------------
// Kernel 2: barrier-free fused cosine-GEMM.
// One block = 64 rows x ALL 1024 cols, 256 threads (4 waves); grid = 512.
// launch_bounds(256,1): R4/R5/R6 showed ANY min-waves>=2 hint makes the
// backend cap arch-VGPRs at 128 and spill the 128-reg accumulator to
// scratch (68 MB writes). With (256,1) the same shape compiles to ~220
// VGPR, no spill (R3); hardware then fits 2 waves/SIMD (512/220) and
// 2 blocks/CU (65 KiB LDS) on its own -- the occupancy the hint was
// supposed to buy, without the register cap.
// Each wave: one 256-col chunk, all 64 rows (4 mf), 2 sub-chunks of 8 nf
// (acc[4][8] = 128 VGPR). A panel LDS-resident (frag-linear, conflict-free);
// B fragments streamed global->registers (L2-resident, 1 MiB).
// grid = 512, block = 256
// ---------------------------------------------------------------------------
__global__ __launch_bounds__(256, 1) void k_gemm(
    const ushort* __restrict__ Af,
    const ushort* __restrict__ Bf,
    const float* __restrict__ wp,
    float* __restrict__ part,    // [NROW] sum of exp over all 1024 cols
    float* __restrict__ diag)    // [NROW] raw cos vs own full centroid
{
  __shared__ ushort ldsA[64 * DIM];    // 64 KiB, fragment-linear
  __shared__ float sPart[64][4];

  const int t = threadIdx.x;
  const int w = t >> 6, lane = t & 63;
  const int lr = lane & 15, lk = lane >> 4;
  const int rblk = blockIdx.x;         // 0..511
  const float W = *wp;

  // stage A panel once: 64 frags x 1 KiB, linear global_load_lds
  {
    const ushort* gsrc = Af + (size_t)rblk * (64 * DIM);
    const int off = t * 8;   // ushort units, lane-contiguous 16B
#pragma unroll
    for (int i = 0; i < 16; ++i)
      GLOAD_LDS16(gsrc + off + i * 2048, ((char*)ldsA) + (off + i * 2048) * 2);
  }
  __syncthreads();   // only barrier before epilogue

  float sum[4][4];
#pragma unroll
  for (int a = 0; a < 4; ++a)
#pragma unroll
    for (int b = 0; b < 4; ++b) sum[a][b] = 0.f;

#pragma unroll
  for (int sub = 0; sub < 2; ++sub) {
    f32x4 acc[4][8];
#pragma unroll
    for (int a = 0; a < 4; ++a)
#pragma unroll
      for (int b = 0; b < 8; ++b) acc[a][b] = (f32x4)0.f;

    // this sub-chunk's 8 B fragments; frag nb stride = 8192 ushorts (<<13)
    const ushort* bp0 = Bf + ((size_t)(w * 16 + sub * 8) << 13) + lane * 8;

#pragma unroll
    for (int kf = 0; kf < 16; ++kf) {
      bf16x8 bfr[8];
#pragma unroll
      for (int nf = 0; nf < 8; ++nf)
        bfr[nf] = *(const bf16x8*)(bp0 + (size_t)((nf * 16 + kf) << 9));
#pragma unroll
      for (int mf = 0; mf < 4; ++mf) {
        const bf16x8 afr =
            *(const bf16x8*)&ldsA[((mf * 16 + kf) << 9) + lane * 8];
#pragma unroll
        for (int nf = 0; nf < 8; ++nf)
          acc[mf][nf] = __builtin_amdgcn_mfma_f32_16x16x32_bf16(
              afr, bfr[nf], acc[mf][nf], 0, 0, 0);
      }
    }

    // fused epilogue: exp((fmax(cos,eps)-1)*W)  [shift w+b cancels in lse]
#pragma unroll
    for (int mf = 0; mf < 4; ++mf)
#pragma unroll
      for (int i = 0; i < 4; ++i) {
#pragma unroll
        for (int nf = 0; nf < 8; ++nf)
          sum[mf][i] += __expf((fmaxf(acc[mf][nf][i], EPS) - 1.f) * W);
      }

    // diag capture: block's 2 speakers c = rblk*2 + sp; col c lives in
    // wave w = c>>8, sub = (c>>7)&1, nf = (c>>4)&7, lanes lr == c&15;
    // its rows are mf = sp*2 + mh (mh=0,1).
#pragma unroll
    for (int sp = 0; sp < 2; ++sp) {
      const int c = rblk * 2 + sp;
      if (w == (c >> 8) && sub == ((c >> 7) & 1)) {
        const int nfo = (c >> 4) & 7;
#pragma unroll
        for (int mh = 0; mh < 2; ++mh) {
          f32x4 dsel = acc[sp * 2 + mh][0];
#pragma unroll
          for (int nf = 1; nf < 8; ++nf)
            if (nf == nfo) dsel = acc[sp * 2 + mh][nf];   // static idx only
          if (lr == (c & 15)) {
#pragma unroll
            for (int i = 0; i < 4; ++i)
              diag[rblk * 64 + (sp * 2 + mh) * 16 + lk * 4 + i] = dsel[i];
          }
        }
      }
    }
  }

  // reduce each row-sum across the 16 lr-lanes
#pragma unroll
  for (int mf = 0; mf < 4; ++mf)
#pragma unroll
    for (int i = 0; i < 4; ++i) {
      float v = sum[mf][i];
      v += __shfl_xor(v, 1);
      v += __shfl_xor(v, 2);
      v += __shfl_xor(v, 4);
      v += __shfl_xor(v, 8);
      sum[mf][i] = v;
    }
  if (lr == 0) {
#pragma unroll
    for (int mf = 0; mf < 4; ++mf)
#pragma unroll
      for (int i = 0; i < 4; ++i)
        sPart[mf * 16 + lk * 4 + i][w] = sum[mf][i];
  }
  __syncthreads();
  if (t < 64)
    part[rblk * 64 + t] =
        sPart[t][0] + sPart[t][1] + sPart[t][2] + sPart[t][3];
}

// ---------------------------------------------------------------------------
// Final: swap exp(diag)->exp(loo), close logsumexp, deterministic 2-stage sum
// L_row = log(part - exp(dt) + exp(lt)) - lt,  x_t = (fmax(x,eps)-1)*W
// ---------------------------------------------------------------------------
__global__ __launch_bounds__(256) void k_final1(
    const float* __restrict__ part, const float* __restrict__ loo,
    const float* __restrict__ diag, const float* __restrict__ wp,
    float* __restrict__ p2)
{
  const int t = threadIdx.x;
  const int r = blockIdx.x * 256 + t;
  const float W = *wp;
  const float lt = (fmaxf(loo[r], EPS) - 1.f) * W;
  const float dt = (fmaxf(diag[r], EPS) - 1.f) * W;
  const float s = part[r] + __expf(lt) - __expf(dt);
  float v = logf(s) - lt;
  __shared__ float red[4];
  for (int off = 32; off; off >>= 1) v += __shfl_down(v, off);
  if ((t & 63) == 0) red[t >> 6] = v;
  __syncthreads();
  if (t == 0) p2[blockIdx.x] = red[0] + red[1] + red[2] + red[3];
}

__global__ __launch_bounds__(128) void k_final2(
    const float* __restrict__ p2, float* __restrict__ out)
{
  const int t = threadIdx.x;
  float v = p2[t];
  for (int off = 32; off; off >>= 1) v += __shfl_down(v, off);
  __shared__ float red[2];
  if ((t & 63) == 0) red[t >> 6] = v;
  __syncthreads();
  if (t == 0) out[0] = red[0] + red[1];
}

extern "C" void kernel_launch(void* const* d_in, const int* in_sizes, int n_in,
                              void* d_out, int out_size, void* d_ws, size_t ws_size,
                              hipStream_t stream) {
  const float* dvecs = (const float*)d_in[0];
  const float* wptr  = (const float*)d_in[1];
  // b cancels algebraically (shift = w+b subtracted and re-added) -> unused
  float* out = (float*)d_out;

  char* ws = (char*)d_ws;
  ushort* Af = (ushort*)ws;  ws += (size_t)NROW * DIM * sizeof(ushort); // 32 MiB
  ushort* Bf = (ushort*)ws;  ws += (size_t)NSPK * DIM * sizeof(ushort); // 1 MiB
  float* loo  = (float*)ws;  ws += (size_t)NROW * sizeof(float);
  float* diag = (float*)ws;  ws += (size_t)NROW * sizeof(float);
  float* part = (float*)ws;  ws += (size_t)NROW * sizeof(float);
  float* p2   = (float*)ws;

  k_prep<<<NSPK, 256, 0, stream>>>(dvecs, Af, Bf, loo);
  k_gemm<<<512, 256, 0, stream>>>(Af, Bf, wptr, part, diag);
  k_final1<<<NROW / 256, 256, 0, stream>>>(part, loo, diag, wptr, p2);
  k_final2<<<1, 128, 0, stream>>>(p2, out);
}